// Round 1
// baseline (47.767 us; speedup 1.0000x reference)
//
#include <hip/hip_runtime.h>

// Problem constants (match reference setup_inputs)
#define PN 16
#define PC 8
#define PH 512
#define PW 1024
#define PJ 8

// ---------------------------------------------------------------------------
// Kernel 1: soft-argmax expected position per row.
// One wave (64 lanes) per (n,c,h) row of W=1024 floats.
// Each lane loads 16 contiguous-per-lane floats via 4x float4 (coalesced:
// 64 lanes * 16B = 1KB per load instruction).
// ---------------------------------------------------------------------------
__global__ __launch_bounds__(256) void pos_kernel(const float* __restrict__ logits,
                                                  float* __restrict__ pos) {
    const int wave = (blockIdx.x * blockDim.x + threadIdx.x) >> 6;  // row id, 0..N*C*H-1
    const int lane = threadIdx.x & 63;

    const float* row = logits + (size_t)wave * PW;

    float v[16];
#pragma unroll
    for (int k = 0; k < 4; ++k) {
        float4 f = *reinterpret_cast<const float4*>(row + k * 256 + lane * 4);
        v[k * 4 + 0] = f.x;
        v[k * 4 + 1] = f.y;
        v[k * 4 + 2] = f.z;
        v[k * 4 + 3] = f.w;
    }

    // row max
    float m = v[0];
#pragma unroll
    for (int i = 1; i < 16; ++i) m = fmaxf(m, v[i]);
#pragma unroll
    for (int off = 32; off > 0; off >>= 1) m = fmaxf(m, __shfl_xor(m, off));

    // sum(exp) and sum(exp * index)
    float s = 0.f, sw = 0.f;
#pragma unroll
    for (int k = 0; k < 4; ++k) {
#pragma unroll
        for (int j = 0; j < 4; ++j) {
            float e = __expf(v[k * 4 + j] - m);
            s += e;
            sw += e * (float)(k * 256 + lane * 4 + j);
        }
    }
#pragma unroll
    for (int off = 32; off > 0; off >>= 1) {
        s += __shfl_xor(s, off);
        sw += __shfl_xor(sw, off);
    }

    if (lane == 0) pos[wave] = sw / s;
}

// ---------------------------------------------------------------------------
// Kernel 2: per-(n,j) masked smooth-L1 partial sums.
// One wave per (n,j). diff[z] = pos[n,ch,z] - pos[n,ch,z+1], z in [start,end).
// Writes (sum, count) pairs to workspace — deterministic (no float atomics).
// ---------------------------------------------------------------------------
__global__ __launch_bounds__(64) void loss_kernel(const float* __restrict__ pos,
                                                  const int* __restrict__ params,
                                                  float* __restrict__ partial) {
    const int nj = blockIdx.x;  // 0..N*J-1
    const int n = nj / PJ;
    const int j = nj % PJ;

    const int start = params[(n * PJ + j) * 3 + 0];
    const int end   = params[(n * PJ + j) * 3 + 1];
    const int ch    = params[(n * PJ + j) * 3 + 2];

    const float* p = pos + ((size_t)n * PC + ch) * PH;

    float sum = 0.f, cnt = 0.f;
    for (int z = start + (int)threadIdx.x; z < end; z += 64) {
        float d = p[z] - p[z + 1];
        float x = fabsf(d);
        sum += (x < 1.f) ? 0.5f * d * d : (x - 0.5f);
        cnt += 1.f;
    }
#pragma unroll
    for (int off = 32; off > 0; off >>= 1) {
        sum += __shfl_xor(sum, off);
        cnt += __shfl_xor(cnt, off);
    }
    if (threadIdx.x == 0) {
        partial[nj * 2 + 0] = sum;
        partial[nj * 2 + 1] = cnt;
    }
}

// ---------------------------------------------------------------------------
// Kernel 3: reduce the 128 (sum,count) pairs -> out[0] = total / count.
// One wave; lane t owns entries t and t+64.
// ---------------------------------------------------------------------------
__global__ __launch_bounds__(64) void finalize_kernel(const float* __restrict__ partial,
                                                      float* __restrict__ out) {
    const int t = threadIdx.x;
    float s = partial[t * 2 + 0] + partial[(t + 64) * 2 + 0];
    float c = partial[t * 2 + 1] + partial[(t + 64) * 2 + 1];
#pragma unroll
    for (int off = 32; off > 0; off >>= 1) {
        s += __shfl_xor(s, off);
        c += __shfl_xor(c, off);
    }
    if (t == 0) out[0] = s / c;
}

extern "C" void kernel_launch(void* const* d_in, const int* in_sizes, int n_in,
                              void* d_out, int out_size, void* d_ws, size_t ws_size,
                              hipStream_t stream) {
    const float* logits = (const float*)d_in[0];
    const int* params = (const int*)d_in[1];
    float* out = (float*)d_out;

    // Workspace layout:
    //   [0 .. N*C*H)              : pos array (65536 floats)
    //   [N*C*H .. N*C*H + 2*N*J)  : per-(n,j) (sum,count) partials
    float* pos = (float*)d_ws;
    float* partial = pos + (size_t)PN * PC * PH;

    const int rows = PN * PC * PH;            // 65536 rows
    const int blocks = rows / 4;              // 4 waves (256 threads) per block
    pos_kernel<<<blocks, 256, 0, stream>>>(logits, pos);
    loss_kernel<<<PN * PJ, 64, 0, stream>>>(pos, params, partial);
    finalize_kernel<<<1, 64, 0, stream>>>(partial, out);
}

// Round 2
// 24.812 us; speedup vs baseline: 1.9251x; 1.9251x over previous
//
#include <hip/hip_runtime.h>

// Problem constants (match reference setup_inputs)
#define PN 16
#define PC 8
#define PH 512
#define PW 1024
#define PJ 8

// ---------------------------------------------------------------------------
// Kernel 1: soft-argmax expected position per row — but ONLY for rows that
// some (n,j) range actually consumes. Each wave checks its (n,c,h) against
// the 8 wave-uniform param triples of its sample and exits early otherwise
// (~75% of rows expected skipped -> ~4x less HBM fetch).
// One wave (64 lanes) per needed (n,c,h) row of W=1024 floats; each lane
// loads 16 floats via 4x float4 (64 lanes * 16B = 1KB per load instr).
// ---------------------------------------------------------------------------
__global__ __launch_bounds__(256) void pos_kernel(const float* __restrict__ logits,
                                                  const int* __restrict__ params,
                                                  float* __restrict__ pos) {
    const int wave = (blockIdx.x * blockDim.x + threadIdx.x) >> 6;  // row id, 0..N*C*H-1
    const int lane = threadIdx.x & 63;

    const int n = wave >> 12;        // C*H = 4096 rows per sample
    const int c = (wave >> 9) & (PC - 1);
    const int h = wave & (PH - 1);

    // Row (n,c,h) is needed iff some j has ch==c and start <= h <= end
    // (inclusive end: diff[z] = pos[z] - pos[z+1] touches rows start..end).
    const int* pp = params + n * PJ * 3;
    bool needed = false;
#pragma unroll
    for (int j = 0; j < PJ; ++j) {
        const int s = pp[j * 3 + 0];
        const int e = pp[j * 3 + 1];
        const int ch = pp[j * 3 + 2];
        needed |= (ch == c) & (h >= s) & (h <= e);
    }
    if (!needed) return;  // wave-uniform exit

    const float* row = logits + (size_t)wave * PW;

    float v[16];
#pragma unroll
    for (int k = 0; k < 4; ++k) {
        float4 f = *reinterpret_cast<const float4*>(row + k * 256 + lane * 4);
        v[k * 4 + 0] = f.x;
        v[k * 4 + 1] = f.y;
        v[k * 4 + 2] = f.z;
        v[k * 4 + 3] = f.w;
    }

    // row max
    float m = v[0];
#pragma unroll
    for (int i = 1; i < 16; ++i) m = fmaxf(m, v[i]);
#pragma unroll
    for (int off = 32; off > 0; off >>= 1) m = fmaxf(m, __shfl_xor(m, off));

    // sum(exp) and sum(exp * index)
    float s = 0.f, sw = 0.f;
#pragma unroll
    for (int k = 0; k < 4; ++k) {
#pragma unroll
        for (int j = 0; j < 4; ++j) {
            float e = __expf(v[k * 4 + j] - m);
            s += e;
            sw += e * (float)(k * 256 + lane * 4 + j);
        }
    }
#pragma unroll
    for (int off = 32; off > 0; off >>= 1) {
        s += __shfl_xor(s, off);
        sw += __shfl_xor(sw, off);
    }

    if (lane == 0) pos[wave] = sw / s;
}

// ---------------------------------------------------------------------------
// Kernel 2: per-(n,j) masked smooth-L1 partial sums.
// One wave per (n,j). diff[z] = pos[n,ch,z] - pos[n,ch,z+1], z in [start,end).
// Writes (sum, count) pairs to workspace — deterministic (no float atomics).
// ---------------------------------------------------------------------------
__global__ __launch_bounds__(64) void loss_kernel(const float* __restrict__ pos,
                                                  const int* __restrict__ params,
                                                  float* __restrict__ partial) {
    const int nj = blockIdx.x;  // 0..N*J-1
    const int n = nj / PJ;
    const int j = nj % PJ;

    const int start = params[(n * PJ + j) * 3 + 0];
    const int end   = params[(n * PJ + j) * 3 + 1];
    const int ch    = params[(n * PJ + j) * 3 + 2];

    const float* p = pos + ((size_t)n * PC + ch) * PH;

    float sum = 0.f, cnt = 0.f;
    for (int z = start + (int)threadIdx.x; z < end; z += 64) {
        float d = p[z] - p[z + 1];
        float x = fabsf(d);
        sum += (x < 1.f) ? 0.5f * d * d : (x - 0.5f);
        cnt += 1.f;
    }
#pragma unroll
    for (int off = 32; off > 0; off >>= 1) {
        sum += __shfl_xor(sum, off);
        cnt += __shfl_xor(cnt, off);
    }
    if (threadIdx.x == 0) {
        partial[nj * 2 + 0] = sum;
        partial[nj * 2 + 1] = cnt;
    }
}

// ---------------------------------------------------------------------------
// Kernel 3: reduce the 128 (sum,count) pairs -> out[0] = total / count.
// One wave; lane t owns entries t and t+64.
// ---------------------------------------------------------------------------
__global__ __launch_bounds__(64) void finalize_kernel(const float* __restrict__ partial,
                                                      float* __restrict__ out) {
    const int t = threadIdx.x;
    float s = partial[t * 2 + 0] + partial[(t + 64) * 2 + 0];
    float c = partial[t * 2 + 1] + partial[(t + 64) * 2 + 1];
#pragma unroll
    for (int off = 32; off > 0; off >>= 1) {
        s += __shfl_xor(s, off);
        c += __shfl_xor(c, off);
    }
    if (t == 0) out[0] = s / c;
}

extern "C" void kernel_launch(void* const* d_in, const int* in_sizes, int n_in,
                              void* d_out, int out_size, void* d_ws, size_t ws_size,
                              hipStream_t stream) {
    const float* logits = (const float*)d_in[0];
    const int* params = (const int*)d_in[1];
    float* out = (float*)d_out;

    // Workspace layout:
    //   [0 .. N*C*H)              : pos array (65536 floats)
    //   [N*C*H .. N*C*H + 2*N*J)  : per-(n,j) (sum,count) partials
    float* pos = (float*)d_ws;
    float* partial = pos + (size_t)PN * PC * PH;

    const int rows = PN * PC * PH;            // 65536 rows
    const int blocks = rows / 4;              // 4 waves (256 threads) per block
    pos_kernel<<<blocks, 256, 0, stream>>>(logits, params, pos);
    loss_kernel<<<PN * PJ, 64, 0, stream>>>(pos, params, partial);
    finalize_kernel<<<1, 64, 0, stream>>>(partial, out);
}